// Round 2
// 385.814 us; speedup vs baseline: 1.0481x; 1.0481x over previous
//
#include <hip/hip_runtime.h>
#include <stdint.h>

#define BB 64
#define CC 256
#define HH 56
#define WW 56
#define HWN 3136          // 56*56
#define NCH (BB*CC)       // 16384
#define TOPK 38
#define NV4 784           // HWN / 4 float4 per channel
#define DD 16             // hidden dim
#define NSEL (BB*TOPK)    // 2432 selected channels total

typedef float floatx4 __attribute__((ext_vector_type(4)));  // clang-native for NT builtins

// ---------------- Pass A: per-channel sum (fp64) + argmax + copy x->out --------------
// The copy makes unselected channels (85%) final here; pass C only fixes up the 15%
// selected channels. Stores are non-temporal so they don't evict x from L2/L3 --
// pass C's re-read of the selected channels should then hit cache.
__global__ __launch_bounds__(256) void reduce_copy_kernel(const float* __restrict__ x,
                                                          float* __restrict__ out,
                                                          double* __restrict__ sums,
                                                          int* __restrict__ amax) {
    const int wave = threadIdx.x >> 6;
    const int lane = threadIdx.x & 63;
    const int ch = blockIdx.x * 4 + wave;              // flat (b,c)
    const floatx4* p = (const floatx4*)(x + (size_t)ch * HWN);
    floatx4* q = (floatx4*)(out + (size_t)ch * HWN);

    double s = 0.0;
    float bv = -INFINITY; int bi = 0x7fffffff;
    for (int i = lane; i < NV4; i += 64) {
        floatx4 v = p[i];
        __builtin_nontemporal_store(v, q + i);         // out = x (bit-exact copy)
        float f[4] = {v.x, v.y, v.z, v.w};
        const int e0 = i * 4;
        #pragma unroll
        for (int j = 0; j < 4; ++j) {
            s += (double)f[j];
            const int ij = e0 + j;
            if (f[j] > bv || (f[j] == bv && ij < bi)) { bv = f[j]; bi = ij; }
        }
    }
    // wave-64 reduction; only lane 0's result is used (identical order to verified ver.)
    for (int off = 32; off >= 1; off >>= 1) {
        s += __shfl_down(s, off, 64);
        float ov = __shfl_down(bv, off, 64);
        int   oi = __shfl_down(bi, off, 64);
        if (ov > bv || (ov == bv && oi < bi)) { bv = ov; bi = oi; }
    }
    if (lane == 0) { sums[ch] = s; amax[ch] = bi; }
}

// ---------------- Pass B: SE module + top-k -> COMPACT selected-channel descriptors --
// Ranks are a strict total order, so the 38 selected channels of batch b get unique
// ranks {0..37} -> deterministic compaction slot b*TOPK + rank, no atomics needed.
__global__ __launch_bounds__(256) void mask_kernel(const double* __restrict__ sums,
                                                   const int* __restrict__ amax,
                                                   const float* __restrict__ w1,
                                                   const float* __restrict__ w2,
                                                   int* __restrict__ sel_ch,
                                                   float* __restrict__ sel_lam,
                                                   uint32_t* __restrict__ sel_box) {
    const int b = blockIdx.x;
    const int c = threadIdx.x;
    __shared__ double pooled[CC];
    __shared__ double hidden[DD];
    __shared__ double Ms[CC];

    pooled[c] = sums[b * CC + c] / (double)HWN;
    __syncthreads();

    if (c < DD) {
        double acc = 0.0;
        for (int j = 0; j < CC; ++j) acc += pooled[j] * (double)w1[c * CC + j];
        hidden[c] = acc > 0.0 ? acc : 0.0;             // relu
    }
    __syncthreads();

    double acc = 0.0;
    for (int d = 0; d < DD; ++d) acc += hidden[d] * (double)w2[c * DD + d];
    double m = 1.0 / (1.0 + exp(-acc));                // sigmoid
    Ms[c] = m;
    __syncthreads();

    // rank with jax top_k tie-break (lower index first among equals)
    int rank = 0;
    for (int j = 0; j < CC; ++j) {
        double mj = Ms[j];
        rank += (mj > m || (mj == m && j < c)) ? 1 : 0;
    }

    if (rank < TOPK) {
        const int idx = amax[b * CC + c];
        const int mh = idx / WW, mw = idx - (idx / WW) * WW;
        const int h1 = mh - 2 > 0 ? mh - 2 : 0;
        const int h2 = mh + 2 < HH - 1 ? mh + 2 : HH - 1;
        const int w1b = mw - 2 > 0 ? mw - 2 : 0;
        const int w2b = mw + 2 < WW - 1 ? mw + 2 : WW - 1;
        const int area = (h2 - h1 + 1) * (w2b - w1b + 1);

        const int slot = b * TOPK + rank;
        sel_ch[slot]  = b * CC + c;
        sel_lam[slot] = (float)HWN / (float)(HWN - area);
        sel_box[slot] = (uint32_t)(h1 | (h2 << 8) | (w1b << 16) | (w2b << 24));
    }
}

// ---------------- Pass C: sparse apply — only the 2432 selected channels -------------
__global__ __launch_bounds__(256) void apply_sel_kernel(const float* __restrict__ x,
                                                        float* __restrict__ out,
                                                        const int* __restrict__ sel_ch,
                                                        const float* __restrict__ sel_lam,
                                                        const uint32_t* __restrict__ sel_box) {
    const int wave = threadIdx.x >> 6;
    const int lane = threadIdx.x & 63;
    const int slot = blockIdx.x * 4 + wave;            // < NSEL (2432 = 608*4 exactly)

    const int ch = sel_ch[slot];
    const float lam = sel_lam[slot];
    const uint32_t box = sel_box[slot];
    const int h1 = box & 0xff, h2 = (box >> 8) & 0xff;
    const int w1b = (box >> 16) & 0xff, w2b = (box >> 24) & 0xff;

    const float4* p = (const float4*)(x + (size_t)ch * HWN);
    float4* q = (float4*)(out + (size_t)ch * HWN);

    for (int i = lane; i < NV4; i += 64) {
        float4 v = p[i];
        const int row = i / 14;                // 14 float4 per 56-wide row; never crosses
        const int cb = (i - row * 14) * 4;     // base column
        const bool inrow = (row >= h1) && (row <= h2);
        float f[4] = {v.x, v.y, v.z, v.w};
        #pragma unroll
        for (int j = 0; j < 4; ++j) {
            const int cj = cb + j;
            f[j] *= lam;
            if (inrow && cj >= w1b && cj <= w2b) f[j] = 0.0f;
        }
        float4 o; o.x = f[0]; o.y = f[1]; o.z = f[2]; o.w = f[3];
        q[i] = o;                              // overwrites the pass-A copy for this ch
    }
}

extern "C" void kernel_launch(void* const* d_in, const int* in_sizes, int n_in,
                              void* d_out, int out_size, void* d_ws, size_t ws_size,
                              hipStream_t stream) {
    const float* x  = (const float*)d_in[0];   // [64,256,56,56] f32
    const float* w1 = (const float*)d_in[1];   // [16,256] f32
    const float* w2 = (const float*)d_in[2];   // [256,16] f32
    float* out = (float*)d_out;                // [64,256,56,56] f32

    char* ws = (char*)d_ws;
    double*   sums    = (double*)(ws);                 // 16384 * 8 = 128 KB
    int*      amax    = (int*)(ws + 131072);           // 16384 * 4 =  64 KB
    int*      sel_ch  = (int*)(ws + 196608);           //  2432 * 4 < 16 KB
    float*    sel_lam = (float*)(ws + 212992);         //  2432 * 4 < 16 KB
    uint32_t* sel_box = (uint32_t*)(ws + 229376);      //  2432 * 4 < 16 KB

    reduce_copy_kernel<<<NCH / 4, 256, 0, stream>>>(x, out, sums, amax);
    mask_kernel<<<BB, 256, 0, stream>>>(sums, amax, w1, w2, sel_ch, sel_lam, sel_box);
    apply_sel_kernel<<<NSEL / 4, 256, 0, stream>>>(x, out, sel_ch, sel_lam, sel_box);
}

// Round 3
// 380.463 us; speedup vs baseline: 1.0629x; 1.0141x over previous
//
#include <hip/hip_runtime.h>
#include <stdint.h>

#define BB 64
#define CC 256
#define HH 56
#define WW 56
#define HWN 3136          // 56*56
#define NCH (BB*CC)       // 16384
#define TOPK 38
#define NV4 784           // HWN / 4 float4 per channel
#define DD 16             // hidden dim
#define NSEL (BB*TOPK)    // 2432 selected channels total
#define KSLOT 13          // ceil(784/64) lane-strided float4 slots per wave-channel

typedef float floatx4 __attribute__((ext_vector_type(4)));  // clang-native for NT builtins

// ---------------- Pass A: per-channel sum (fp64) + argmax + copy x->out --------------
// One wave per channel. ALL 13 float4 loads are issued before any consume (52 data
// VGPRs) so each wave keeps ~13 KB in flight -> HBM-BW-bound, not latency-bound.
// (Previous version compiled to VGPR_Count=12 => single load in flight => 2.3 TB/s.)
// Accumulation order is element-ascending per lane, identical to the verified kernel.
__global__ __launch_bounds__(256) void reduce_copy_kernel(const float* __restrict__ x,
                                                          float* __restrict__ out,
                                                          double* __restrict__ sums,
                                                          int* __restrict__ amax) {
    const int wave = threadIdx.x >> 6;
    const int lane = threadIdx.x & 63;
    const int ch = blockIdx.x * 4 + wave;              // flat (b,c)
    const floatx4* p = (const floatx4*)(x + (size_t)ch * HWN);
    floatx4* q = (floatx4*)(out + (size_t)ch * HWN);

    floatx4 v[KSLOT];
    #pragma unroll
    for (int k = 0; k < KSLOT; ++k) {                  // issue ALL loads first
        const int i = lane + (k << 6);
        if (k < KSLOT - 1 || lane < 16) v[k] = p[i];   // 784 = 12*64 + 16
    }
    #pragma unroll
    for (int k = 0; k < KSLOT; ++k) {                  // stream the copy out (NT: keep
        const int i = lane + (k << 6);                 //  x resident in L3 for pass C)
        if (k < KSLOT - 1 || lane < 16) __builtin_nontemporal_store(v[k], q + i);
    }

    double s = 0.0;
    float bv = -INFINITY; int bi = 0x7fffffff;
    #pragma unroll
    for (int k = 0; k < KSLOT; ++k) {
        const int i = lane + (k << 6);
        if (k < KSLOT - 1 || lane < 16) {
            float f[4] = {v[k].x, v[k].y, v[k].z, v[k].w};
            const int e0 = i * 4;
            #pragma unroll
            for (int j = 0; j < 4; ++j) {              // exact order of verified kernel
                s += (double)f[j];
                const int ij = e0 + j;
                if (f[j] > bv || (f[j] == bv && ij < bi)) { bv = f[j]; bi = ij; }
            }
        }
    }
    // wave-64 reduction; only lane 0's result is used (identical order to verified ver.)
    for (int off = 32; off >= 1; off >>= 1) {
        s += __shfl_down(s, off, 64);
        float ov = __shfl_down(bv, off, 64);
        int   oi = __shfl_down(bi, off, 64);
        if (ov > bv || (ov == bv && oi < bi)) { bv = ov; bi = oi; }
    }
    if (lane == 0) { sums[ch] = s; amax[ch] = bi; }
}

// ---------------- Pass B: SE module + top-k -> COMPACT selected-channel descriptors --
// Ranks are a strict total order, so the 38 selected channels of batch b get unique
// ranks {0..37} -> deterministic compaction slot b*TOPK + rank, no atomics needed.
__global__ __launch_bounds__(256) void mask_kernel(const double* __restrict__ sums,
                                                   const int* __restrict__ amax,
                                                   const float* __restrict__ w1,
                                                   const float* __restrict__ w2,
                                                   int* __restrict__ sel_ch,
                                                   float* __restrict__ sel_lam,
                                                   uint32_t* __restrict__ sel_box) {
    const int b = blockIdx.x;
    const int c = threadIdx.x;
    __shared__ double pooled[CC];
    __shared__ double hidden[DD];
    __shared__ double Ms[CC];

    pooled[c] = sums[b * CC + c] / (double)HWN;
    __syncthreads();

    if (c < DD) {
        double acc = 0.0;
        for (int j = 0; j < CC; ++j) acc += pooled[j] * (double)w1[c * CC + j];
        hidden[c] = acc > 0.0 ? acc : 0.0;             // relu
    }
    __syncthreads();

    double acc = 0.0;
    for (int d = 0; d < DD; ++d) acc += hidden[d] * (double)w2[c * DD + d];
    double m = 1.0 / (1.0 + exp(-acc));                // sigmoid
    Ms[c] = m;
    __syncthreads();

    // rank with jax top_k tie-break (lower index first among equals)
    int rank = 0;
    for (int j = 0; j < CC; ++j) {
        double mj = Ms[j];
        rank += (mj > m || (mj == m && j < c)) ? 1 : 0;
    }

    if (rank < TOPK) {
        const int idx = amax[b * CC + c];
        const int mh = idx / WW, mw = idx - (idx / WW) * WW;
        const int h1 = mh - 2 > 0 ? mh - 2 : 0;
        const int h2 = mh + 2 < HH - 1 ? mh + 2 : HH - 1;
        const int w1b = mw - 2 > 0 ? mw - 2 : 0;
        const int w2b = mw + 2 < WW - 1 ? mw + 2 : WW - 1;
        const int area = (h2 - h1 + 1) * (w2b - w1b + 1);

        const int slot = b * TOPK + rank;
        sel_ch[slot]  = b * CC + c;
        sel_lam[slot] = (float)HWN / (float)(HWN - area);
        sel_box[slot] = (uint32_t)(h1 | (h2 << 8) | (w1b << 16) | (w2b << 24));
    }
}

// ---------------- Pass C: sparse apply — only the 2432 selected channels -------------
// Same all-loads-first structure; x re-read here should largely hit L3.
__global__ __launch_bounds__(256) void apply_sel_kernel(const float* __restrict__ x,
                                                        float* __restrict__ out,
                                                        const int* __restrict__ sel_ch,
                                                        const float* __restrict__ sel_lam,
                                                        const uint32_t* __restrict__ sel_box) {
    const int wave = threadIdx.x >> 6;
    const int lane = threadIdx.x & 63;
    const int slot = blockIdx.x * 4 + wave;            // < NSEL (2432 = 608*4 exactly)

    const int ch = sel_ch[slot];
    const float lam = sel_lam[slot];
    const uint32_t box = sel_box[slot];
    const int h1 = box & 0xff, h2 = (box >> 8) & 0xff;
    const int w1b = (box >> 16) & 0xff, w2b = (box >> 24) & 0xff;

    const floatx4* p = (const floatx4*)(x + (size_t)ch * HWN);
    floatx4* q = (floatx4*)(out + (size_t)ch * HWN);

    floatx4 v[KSLOT];
    #pragma unroll
    for (int k = 0; k < KSLOT; ++k) {
        const int i = lane + (k << 6);
        if (k < KSLOT - 1 || lane < 16) v[k] = p[i];
    }

    #pragma unroll
    for (int k = 0; k < KSLOT; ++k) {
        const int i = lane + (k << 6);
        if (k < KSLOT - 1 || lane < 16) {
            const int row = i / 14;            // 14 float4 per 56-wide row; never crosses
            const int cb = (i - row * 14) * 4; // base column
            const bool inrow = (row >= h1) && (row <= h2);
            float f[4] = {v[k].x, v[k].y, v[k].z, v[k].w};
            #pragma unroll
            for (int j = 0; j < 4; ++j) {
                const int cj = cb + j;
                f[j] *= lam;
                if (inrow && cj >= w1b && cj <= w2b) f[j] = 0.0f;
            }
            floatx4 o; o.x = f[0]; o.y = f[1]; o.z = f[2]; o.w = f[3];
            __builtin_nontemporal_store(o, q + i); // overwrites pass-A copy for this ch
        }
    }
}

extern "C" void kernel_launch(void* const* d_in, const int* in_sizes, int n_in,
                              void* d_out, int out_size, void* d_ws, size_t ws_size,
                              hipStream_t stream) {
    const float* x  = (const float*)d_in[0];   // [64,256,56,56] f32
    const float* w1 = (const float*)d_in[1];   // [16,256] f32
    const float* w2 = (const float*)d_in[2];   // [256,16] f32
    float* out = (float*)d_out;                // [64,256,56,56] f32

    char* ws = (char*)d_ws;
    double*   sums    = (double*)(ws);                 // 16384 * 8 = 128 KB
    int*      amax    = (int*)(ws + 131072);           // 16384 * 4 =  64 KB
    int*      sel_ch  = (int*)(ws + 196608);           //  2432 * 4 < 16 KB
    float*    sel_lam = (float*)(ws + 212992);         //  2432 * 4 < 16 KB
    uint32_t* sel_box = (uint32_t*)(ws + 229376);      //  2432 * 4 < 16 KB

    reduce_copy_kernel<<<NCH / 4, 256, 0, stream>>>(x, out, sums, amax);
    mask_kernel<<<BB, 256, 0, stream>>>(sums, amax, w1, w2, sel_ch, sel_lam, sel_box);
    apply_sel_kernel<<<NSEL / 4, 256, 0, stream>>>(x, out, sel_ch, sel_lam, sel_box);
}

// Round 4
// 377.182 us; speedup vs baseline: 1.0721x; 1.0087x over previous
//
#include <hip/hip_runtime.h>
#include <stdint.h>

#define BB 64
#define CC 256
#define HH 56
#define WW 56
#define HWN 3136          // 56*56
#define NCH (BB*CC)       // 16384
#define TOPK 38
#define NV4 784           // HWN / 4 float4 per channel
#define DD 16             // hidden dim
#define NSEL (BB*TOPK)    // 2432 selected channels total
#define KSLOT 13          // ceil(784/64) lane-strided float4 slots per wave-channel

typedef float floatx4 __attribute__((ext_vector_type(4)));

// ---------------- Pass A: per-channel sum (fp64) + argmax + copy x->out --------------
// One wave per channel, all loads issued before consumption. Stores are PLAIN (not
// non-temporal): NT stores measured 2.3-2.4 TB/s regardless of in-flight depth while
// the rocclr fill kernel sustains 6.6 TB/s with plain stores -> NT path was the cap.
__global__ __launch_bounds__(256) void reduce_copy_kernel(const float* __restrict__ x,
                                                          float* __restrict__ out,
                                                          double* __restrict__ sums,
                                                          int* __restrict__ amax) {
    const int wave = threadIdx.x >> 6;
    const int lane = threadIdx.x & 63;
    const int ch = blockIdx.x * 4 + wave;              // flat (b,c)
    const floatx4* p = (const floatx4*)(x + (size_t)ch * HWN);
    floatx4* q = (floatx4*)(out + (size_t)ch * HWN);

    floatx4 v[KSLOT];
    #pragma unroll
    for (int k = 0; k < KSLOT; ++k) {                  // issue ALL loads first
        const int i = lane + (k << 6);
        if (k < KSLOT - 1 || lane < 16) v[k] = p[i];   // 784 = 12*64 + 16
    }
    #pragma unroll
    for (int k = 0; k < KSLOT; ++k) {                  // stream the copy out
        const int i = lane + (k << 6);
        if (k < KSLOT - 1 || lane < 16) q[i] = v[k];
    }

    double s = 0.0;
    float bv = -INFINITY; int bi = 0x7fffffff;
    #pragma unroll
    for (int k = 0; k < KSLOT; ++k) {
        const int i = lane + (k << 6);
        if (k < KSLOT - 1 || lane < 16) {
            float f[4] = {v[k].x, v[k].y, v[k].z, v[k].w};
            const int e0 = i * 4;
            #pragma unroll
            for (int j = 0; j < 4; ++j) {              // exact order of verified kernel
                s += (double)f[j];
                const int ij = e0 + j;
                if (f[j] > bv || (f[j] == bv && ij < bi)) { bv = f[j]; bi = ij; }
            }
        }
    }
    // wave-64 reduction; only lane 0's result is used (identical order to verified ver.)
    for (int off = 32; off >= 1; off >>= 1) {
        s += __shfl_down(s, off, 64);
        float ov = __shfl_down(bv, off, 64);
        int   oi = __shfl_down(bi, off, 64);
        if (ov > bv || (ov == bv && oi < bi)) { bv = ov; bi = oi; }
    }
    if (lane == 0) { sums[ch] = s; amax[ch] = bi; }
}

// ---------------- Pass B: SE module + top-k -> COMPACT selected-channel descriptors --
// Ranks are a strict total order, so the 38 selected channels of batch b get unique
// ranks {0..37} -> deterministic compaction slot b*TOPK + rank, no atomics needed.
__global__ __launch_bounds__(256) void mask_kernel(const double* __restrict__ sums,
                                                   const int* __restrict__ amax,
                                                   const float* __restrict__ w1,
                                                   const float* __restrict__ w2,
                                                   int* __restrict__ sel_ch,
                                                   float* __restrict__ sel_lam,
                                                   uint32_t* __restrict__ sel_box) {
    const int b = blockIdx.x;
    const int c = threadIdx.x;
    __shared__ double pooled[CC];
    __shared__ double hidden[DD];
    __shared__ double Ms[CC];

    pooled[c] = sums[b * CC + c] / (double)HWN;
    __syncthreads();

    if (c < DD) {
        double acc = 0.0;
        for (int j = 0; j < CC; ++j) acc += pooled[j] * (double)w1[c * CC + j];
        hidden[c] = acc > 0.0 ? acc : 0.0;             // relu
    }
    __syncthreads();

    double acc = 0.0;
    for (int d = 0; d < DD; ++d) acc += hidden[d] * (double)w2[c * DD + d];
    double m = 1.0 / (1.0 + exp(-acc));                // sigmoid
    Ms[c] = m;
    __syncthreads();

    // rank with jax top_k tie-break (lower index first among equals)
    int rank = 0;
    for (int j = 0; j < CC; ++j) {
        double mj = Ms[j];
        rank += (mj > m || (mj == m && j < c)) ? 1 : 0;
    }

    if (rank < TOPK) {
        const int idx = amax[b * CC + c];
        const int mh = idx / WW, mw = idx - (idx / WW) * WW;
        const int h1 = mh - 2 > 0 ? mh - 2 : 0;
        const int h2 = mh + 2 < HH - 1 ? mh + 2 : HH - 1;
        const int w1b = mw - 2 > 0 ? mw - 2 : 0;
        const int w2b = mw + 2 < WW - 1 ? mw + 2 : WW - 1;
        const int area = (h2 - h1 + 1) * (w2b - w1b + 1);

        const int slot = b * TOPK + rank;
        sel_ch[slot]  = b * CC + c;
        sel_lam[slot] = (float)HWN / (float)(HWN - area);
        sel_box[slot] = (uint32_t)(h1 | (h2 << 8) | (w1b << 16) | (w2b << 24));
    }
}

// ---------------- Pass C: sparse apply — only the 2432 selected channels -------------
__global__ __launch_bounds__(256) void apply_sel_kernel(const float* __restrict__ x,
                                                        float* __restrict__ out,
                                                        const int* __restrict__ sel_ch,
                                                        const float* __restrict__ sel_lam,
                                                        const uint32_t* __restrict__ sel_box) {
    const int wave = threadIdx.x >> 6;
    const int lane = threadIdx.x & 63;
    const int slot = blockIdx.x * 4 + wave;            // < NSEL (2432 = 608*4 exactly)

    const int ch = sel_ch[slot];
    const float lam = sel_lam[slot];
    const uint32_t box = sel_box[slot];
    const int h1 = box & 0xff, h2 = (box >> 8) & 0xff;
    const int w1b = (box >> 16) & 0xff, w2b = (box >> 24) & 0xff;

    const floatx4* p = (const floatx4*)(x + (size_t)ch * HWN);
    floatx4* q = (floatx4*)(out + (size_t)ch * HWN);

    floatx4 v[KSLOT];
    #pragma unroll
    for (int k = 0; k < KSLOT; ++k) {
        const int i = lane + (k << 6);
        if (k < KSLOT - 1 || lane < 16) v[k] = p[i];
    }

    #pragma unroll
    for (int k = 0; k < KSLOT; ++k) {
        const int i = lane + (k << 6);
        if (k < KSLOT - 1 || lane < 16) {
            const int row = i / 14;            // 14 float4 per 56-wide row; never crosses
            const int cb = (i - row * 14) * 4; // base column
            const bool inrow = (row >= h1) && (row <= h2);
            float f[4] = {v[k].x, v[k].y, v[k].z, v[k].w};
            #pragma unroll
            for (int j = 0; j < 4; ++j) {
                const int cj = cb + j;
                f[j] *= lam;
                if (inrow && cj >= w1b && cj <= w2b) f[j] = 0.0f;
            }
            floatx4 o; o.x = f[0]; o.y = f[1]; o.z = f[2]; o.w = f[3];
            q[i] = o;                          // overwrites the pass-A copy for this ch
        }
    }
}

extern "C" void kernel_launch(void* const* d_in, const int* in_sizes, int n_in,
                              void* d_out, int out_size, void* d_ws, size_t ws_size,
                              hipStream_t stream) {
    const float* x  = (const float*)d_in[0];   // [64,256,56,56] f32
    const float* w1 = (const float*)d_in[1];   // [16,256] f32
    const float* w2 = (const float*)d_in[2];   // [256,16] f32
    float* out = (float*)d_out;                // [64,256,56,56] f32

    char* ws = (char*)d_ws;
    double*   sums    = (double*)(ws);                 // 16384 * 8 = 128 KB
    int*      amax    = (int*)(ws + 131072);           // 16384 * 4 =  64 KB
    int*      sel_ch  = (int*)(ws + 196608);           //  2432 * 4 < 16 KB
    float*    sel_lam = (float*)(ws + 212992);         //  2432 * 4 < 16 KB
    uint32_t* sel_box = (uint32_t*)(ws + 229376);      //  2432 * 4 < 16 KB

    reduce_copy_kernel<<<NCH / 4, 256, 0, stream>>>(x, out, sums, amax);
    mask_kernel<<<BB, 256, 0, stream>>>(sums, amax, w1, w2, sel_ch, sel_lam, sel_box);
    apply_sel_kernel<<<NSEL / 4, 256, 0, stream>>>(x, out, sel_ch, sel_lam, sel_box);
}